// Round 6
// baseline (136.808 us; speedup 1.0000x reference)
//
#include <hip/hip_runtime.h>
#include <hip/hip_bf16.h>

#define GRID_RES 32
#define GRID_DIM 8
#define N_CELLS  256
#define EMB_VOL  512
#define TAB_N    (GRID_RES * GRID_RES * GRID_RES)   // 32768
#define NPT      4
#define BLOCK    512

// ---------- pre-pass: build bf16 shifted z-pair table in d_ws ----------
// Layout per allocated block b (512 uints = 2KB):
//   pb[b*512 + row*8 + k]   k=0..3: rowA uint k = (bf16 e[2k]) | (bf16 e[2k+1])<<16
//                           k=4..7: rowB uint j = (bf16 e[2j+1]) | (bf16 e[2j+2])<<16
//   where e[8] = +z neighbor block's (lx,ly,0), 0 if neighbor unallocated.
// A z-pair at base lz is ONE aligned dword: zoff = (lz&1) ? 4+(lz>>1) : (lz>>1).

__device__ __forceinline__ unsigned bf16rne(float f) {
    unsigned u = __float_as_uint(f);
    return (u + 0x7fffu + ((u >> 16) & 1u)) >> 16;
}

__global__ __launch_bounds__(256) void build_pairs(
    const float* __restrict__ emb, const int* __restrict__ table,
    unsigned* __restrict__ pb)
{
    int tid = blockIdx.x * 256 + threadIdx.x;
    int entry = tid >> 6;
    if (entry >= TAB_N) return;
    int row = tid & 63;
    int b = table[entry];
    if (b < 0) return;
    int BZ = entry & (GRID_RES - 1);
    int zn = (BZ < GRID_RES - 1) ? table[entry + 1] : -1;

    const float* src = emb + (size_t)b * EMB_VOL + row * 8;
    float4 a0 = *reinterpret_cast<const float4*>(src);
    float4 a1 = *reinterpret_cast<const float4*>(src + 4);
    float e0=a0.x, e1=a0.y, e2=a0.z, e3=a0.w;
    float e4=a1.x, e5=a1.y, e6=a1.z, e7=a1.w;
    float e8 = (zn >= 0) ? emb[(size_t)zn * EMB_VOL + row * 8] : 0.0f;

    unsigned o0 = bf16rne(e0) | (bf16rne(e1) << 16);
    unsigned o1 = bf16rne(e2) | (bf16rne(e3) << 16);
    unsigned o2 = bf16rne(e4) | (bf16rne(e5) << 16);
    unsigned o3 = bf16rne(e6) | (bf16rne(e7) << 16);
    unsigned o4 = bf16rne(e1) | (bf16rne(e2) << 16);
    unsigned o5 = bf16rne(e3) | (bf16rne(e4) << 16);
    unsigned o6 = bf16rne(e5) | (bf16rne(e6) << 16);
    unsigned o7 = bf16rne(e7) | (bf16rne(e8) << 16);

    uint4* dst = reinterpret_cast<uint4*>(pb + (size_t)b * EMB_VOL + row * 8);
    dst[0] = make_uint4(o0, o1, o2, o3);
    dst[1] = make_uint4(o4, o5, o6, o7);
}

// ---------- main: persistent, LDS table, 4 pair-gathers per point ----------
__global__ __launch_bounds__(BLOCK) void interp_pairs(
    const float* __restrict__ positions,
    const float* __restrict__ emb,          // fp32 originals (rare fallback)
    const int*   __restrict__ table,
    const unsigned* __restrict__ pb,
    float* __restrict__ out, int n)
{
    __shared__ short stab[TAB_N];           // 64 KB
    {
        const int4* t4 = reinterpret_cast<const int4*>(table);
        for (int k = threadIdx.x; k < TAB_N / 4; k += BLOCK) {
            int4 v = t4[k];
            short4 s;
            s.x = (short)v.x; s.y = (short)v.y; s.z = (short)v.z; s.w = (short)v.w;
            *reinterpret_cast<short4*>(&stab[4 * k]) = s;
        }
    }
    __syncthreads();

    int nq = (n + NPT - 1) / NPT;
    int stride = gridDim.x * BLOCK;
    for (int q = blockIdx.x * BLOCK + threadIdx.x; q < nq; q += stride) {
        int i0 = q * NPT;
        bool full = (i0 + NPT <= n);

        float px[NPT], py[NPT], pz[NPT];
        if (full) {
            const float4* p4 = reinterpret_cast<const float4*>(positions + 3 * (size_t)i0);
            float4 A = p4[0], B = p4[1], C = p4[2];
            px[0]=A.x; py[0]=A.y; pz[0]=A.z;
            px[1]=A.w; py[1]=B.x; pz[1]=B.y;
            px[2]=B.z; py[2]=B.w; pz[2]=C.x;
            px[3]=C.y; py[3]=C.z; pz[3]=C.w;
        } else {
#pragma unroll
            for (int p = 0; p < NPT; ++p) {
                int ip = min(i0 + p, n - 1);
                px[p] = positions[3 * ip + 0];
                py[p] = positions[3 * ip + 1];
                pz[p] = positions[3 * ip + 2];
            }
        }

        float wA[NPT][3], wB[NPT][3];
        int tb[NPT][4], tb1[NPT][4];
        unsigned lx4[NPT];     // 4x packed lxly (8 bits each)
        int lzv[NPT];
        unsigned uu[NPT][4];

#pragma unroll
        for (int p = 0; p < NPT; ++p) {
            float xc[3];
            xc[0] = (px[p] + 1.0f) * 0.5f * (float)(N_CELLS - 1);
            xc[1] = (py[p] + 1.0f) * 0.5f * (float)(N_CELLS - 1);
            xc[2] = (pz[p] + 1.0f) * 0.5f * (float)(N_CELLS - 1);
            int base[3];
#pragma unroll
            for (int a = 0; a < 3; ++a) {
                float bf = fminf(fmaxf(floorf(xc[a]), 0.0f), (float)(N_CELLS - 2));
                float fr = xc[a] - bf;
                wA[p][a] = 1.0f - fr;
                wB[p][a] = fr;
                base[a] = (int)bf;
            }
            int bx = base[0], by = base[1], bz = base[2];
            lzv[p] = bz & 7;
            int bzs0 = bz >> 3, bzs1 = (bz + 1) >> 3;
            unsigned pk = 0;
#pragma unroll
            for (int c = 0; c < 4; ++c) {
                int dx = c >> 1, dy = c & 1;
                int cx = bx + dx, cy = by + dy;
                int tbase = ((cx >> 3) * GRID_RES + (cy >> 3)) * GRID_RES;
                tb [p][c] = stab[tbase + bzs0];
                tb1[p][c] = stab[tbase + bzs1];
                unsigned lxly = (unsigned)((cx & 7) * 8 + (cy & 7));
                pk |= lxly << (8 * c);
            }
            lx4[p] = pk;
        }

        // all 16 pair-gathers (one aligned dword each), branchless
#pragma unroll
        for (int p = 0; p < NPT; ++p) {
            int lz = lzv[p];
            int zoff = (lz & 1) ? 4 + (lz >> 1) : (lz >> 1);
#pragma unroll
            for (int c = 0; c < 4; ++c) {
                int b = tb[p][c] > 0 ? tb[p][c] : 0;
                int lxly = (lx4[p] >> (8 * c)) & 0xff;
                uu[p][c] = pb[(size_t)b * EMB_VOL + lxly * 8 + zoff];
            }
        }

        const float scale = 0.5f * (float)(N_CELLS - 1);  // 127.5
        float acc[NPT], gxv[NPT], gyv[NPT], gzv[NPT], mk[NPT];

#pragma unroll
        for (int p = 0; p < NPT; ++p) {
            float wz0 = wA[p][2], wz1 = wB[p][2];
            float a = 0.0f, gx = 0.0f, gy = 0.0f, gz = 0.0f;
            bool vall = true;
#pragma unroll
            for (int c = 0; c < 4; ++c) {
                int dx = c >> 1, dy = c & 1;
                bool v0 = tb [p][c] >= 0;
                bool v1 = tb1[p][c] >= 0;
                vall = vall && v0 && v1;
                unsigned u = uu[p][c];
                float e0 = v0 ? __uint_as_float(u << 16) : 0.0f;
                float e1 = v0 ? __uint_as_float(u & 0xffff0000u) : 0.0f;
                // pair-base block invalid but z+1 neighbor valid: only possible
                // at z-crossing (lz==7); fetch that one corner from fp32 source
                if (!v0 && v1) {
                    int lxly = (lx4[p] >> (8 * c)) & 0xff;
                    e1 = emb[(size_t)tb1[p][c] * EMB_VOL + lxly * 8];
                }
                float s = wz0 * e0 + wz1 * e1;
                float wx = dx ? wB[p][0] : wA[p][0];
                float wy = dy ? wB[p][1] : wA[p][1];
                float wxy = wx * wy;
                a  += wxy * s;
                gx += dx ? wy * s : -wy * s;
                gy += dy ? wx * s : -wx * s;
                gz += wxy * (e1 - e0);
            }
            acc[p] = a;
            gxv[p] = scale * gx;
            gyv[p] = scale * gy;
            gzv[p] = scale * gz;
            mk[p]  = vall ? 1.0f : 0.0f;
        }

        float* out_emb  = out;
        float* out_grad = out + (size_t)n;
        float* out_mask = out + 4 * (size_t)n;

        if (full) {
            *reinterpret_cast<float4*>(out_emb + i0) =
                make_float4(acc[0], acc[1], acc[2], acc[3]);
            float4* g4 = reinterpret_cast<float4*>(out_grad + 3 * (size_t)i0);
            g4[0] = make_float4(gxv[0], gyv[0], gzv[0], gxv[1]);
            g4[1] = make_float4(gyv[1], gzv[1], gxv[2], gyv[2]);
            g4[2] = make_float4(gzv[2], gxv[3], gyv[3], gzv[3]);
            *reinterpret_cast<float4*>(out_mask + i0) =
                make_float4(mk[0], mk[1], mk[2], mk[3]);
        } else {
#pragma unroll
            for (int p = 0; p < NPT; ++p) {
                int ip = i0 + p;
                if (ip < n) {
                    out_emb[ip]          = acc[p];
                    out_grad[3 * ip + 0] = gxv[p];
                    out_grad[3 * ip + 1] = gyv[p];
                    out_grad[3 * ip + 2] = gzv[p];
                    out_mask[ip]         = mk[p];
                }
            }
        }
    }
}

// ---------- fallback (R5 kernel) if ws_size is too small ----------
__global__ __launch_bounds__(BLOCK) void neural_poisson_interp(
    const float* __restrict__ positions,
    const float* __restrict__ embeddings,
    const int*   __restrict__ block_table,
    float* __restrict__ out, int n)
{
    __shared__ short stab[TAB_N];
    {
        const int4* t4 = reinterpret_cast<const int4*>(block_table);
        for (int k = threadIdx.x; k < TAB_N / 4; k += BLOCK) {
            int4 v = t4[k];
            short4 s;
            s.x = (short)v.x; s.y = (short)v.y; s.z = (short)v.z; s.w = (short)v.w;
            *reinterpret_cast<short4*>(&stab[4 * k]) = s;
        }
    }
    __syncthreads();

    int t = blockIdx.x * blockDim.x + threadIdx.x;
    int i0 = t * NPT;
    if (i0 >= n) return;
    bool full = (i0 + NPT <= n);

    float px[NPT], py[NPT], pz[NPT];
    if (full) {
        const float4* p4 = reinterpret_cast<const float4*>(positions + 3 * (size_t)i0);
        float4 A = p4[0], B = p4[1], C = p4[2];
        px[0]=A.x; py[0]=A.y; pz[0]=A.z;
        px[1]=A.w; py[1]=B.x; pz[1]=B.y;
        px[2]=B.z; py[2]=B.w; pz[2]=C.x;
        px[3]=C.y; py[3]=C.z; pz[3]=C.w;
    } else {
#pragma unroll
        for (int p = 0; p < NPT; ++p) {
            int ip = min(i0 + p, n - 1);
            px[p] = positions[3 * ip + 0];
            py[p] = positions[3 * ip + 1];
            pz[p] = positions[3 * ip + 2];
        }
    }

    float wA[NPT][3], wB[NPT][3];
    int bidx[NPT][8];
    int li[NPT][8];
#pragma unroll
    for (int p = 0; p < NPT; ++p) {
        float xc[3];
        xc[0] = (px[p] + 1.0f) * 0.5f * 255.0f;
        xc[1] = (py[p] + 1.0f) * 0.5f * 255.0f;
        xc[2] = (pz[p] + 1.0f) * 0.5f * 255.0f;
        int base[3];
#pragma unroll
        for (int a = 0; a < 3; ++a) {
            float bf = fminf(fmaxf(floorf(xc[a]), 0.0f), 254.0f);
            float fr = xc[a] - bf;
            wA[p][a] = 1.0f - fr;
            wB[p][a] = fr;
            base[a] = (int)bf;
        }
#pragma unroll
        for (int c = 0; c < 8; ++c) {
            int dx = (c >> 2) & 1, dy = (c >> 1) & 1, dz = c & 1;
            int cx = base[0] + dx, cy = base[1] + dy, cz = base[2] + dz;
            bidx[p][c] = stab[((cx >> 3) * GRID_RES + (cy >> 3)) * GRID_RES + (cz >> 3)];
            li[p][c] = ((cx & 7) * GRID_DIM + (cy & 7)) * GRID_DIM + (cz & 7);
        }
    }
    float e[NPT][8];
#pragma unroll
    for (int p = 0; p < NPT; ++p)
#pragma unroll
        for (int c = 0; c < 8; ++c) {
            int b = bidx[p][c] > 0 ? bidx[p][c] : 0;
            e[p][c] = embeddings[b * EMB_VOL + li[p][c]];
        }
    const float scale = 127.5f;
    float acc[NPT], gxv[NPT], gyv[NPT], gzv[NPT], mk[NPT];
#pragma unroll
    for (int p = 0; p < NPT; ++p) {
        float a = 0.0f, gx = 0.0f, gy = 0.0f, gz = 0.0f;
        bool vall = true;
#pragma unroll
        for (int c = 0; c < 8; ++c) {
            int dx = (c >> 2) & 1, dy = (c >> 1) & 1, dz = c & 1;
            bool valid = bidx[p][c] >= 0;
            vall = vall && valid;
            float ev = valid ? e[p][c] : 0.0f;
            float wx = dx ? wB[p][0] : wA[p][0];
            float wy = dy ? wB[p][1] : wA[p][1];
            float wz = dz ? wB[p][2] : wA[p][2];
            a += wx * wy * wz * ev;
            float tgx = wy * wz * ev;
            float tgy = wx * wz * ev;
            float tgz = wx * wy * ev;
            gx += dx ? tgx : -tgx;
            gy += dy ? tgy : -tgy;
            gz += dz ? tgz : -tgz;
        }
        acc[p] = a; gxv[p] = scale * gx; gyv[p] = scale * gy; gzv[p] = scale * gz;
        mk[p] = vall ? 1.0f : 0.0f;
    }
    float* out_emb  = out;
    float* out_grad = out + (size_t)n;
    float* out_mask = out + 4 * (size_t)n;
    if (full) {
        *reinterpret_cast<float4*>(out_emb + i0) =
            make_float4(acc[0], acc[1], acc[2], acc[3]);
        float4* g4 = reinterpret_cast<float4*>(out_grad + 3 * (size_t)i0);
        g4[0] = make_float4(gxv[0], gyv[0], gzv[0], gxv[1]);
        g4[1] = make_float4(gyv[1], gzv[1], gxv[2], gyv[2]);
        g4[2] = make_float4(gzv[2], gxv[3], gyv[3], gzv[3]);
        *reinterpret_cast<float4*>(out_mask + i0) =
            make_float4(mk[0], mk[1], mk[2], mk[3]);
    } else {
#pragma unroll
        for (int p = 0; p < NPT; ++p) {
            int ip = i0 + p;
            if (ip < n) {
                out_emb[ip] = acc[p];
                out_grad[3 * ip + 0] = gxv[p];
                out_grad[3 * ip + 1] = gyv[p];
                out_grad[3 * ip + 2] = gzv[p];
                out_mask[ip] = mk[p];
            }
        }
    }
}

extern "C" void kernel_launch(void* const* d_in, const int* in_sizes, int n_in,
                              void* d_out, int out_size, void* d_ws, size_t ws_size,
                              hipStream_t stream) {
    const float* positions   = (const float*)d_in[0];
    const float* embeddings  = (const float*)d_in[1];
    const int*   block_table = (const int*)d_in[2];

    int n = in_sizes[0] / 3;
    int nblocks = in_sizes[1] / EMB_VOL;     // EMB_DIM == 1
    size_t pair_bytes = (size_t)nblocks * EMB_VOL * sizeof(unsigned);
    float* out = (float*)d_out;

    if (ws_size >= pair_bytes) {
        unsigned* pb = (unsigned*)d_ws;
        build_pairs<<<(TAB_N * 64 + 255) / 256, 256, 0, stream>>>(
            embeddings, block_table, pb);
        int nq = (n + NPT - 1) / NPT;
        int grid = 512;                       // 2 WGs/CU, persistent
        int maxg = (nq + BLOCK - 1) / BLOCK;
        if (grid > maxg) grid = maxg;
        interp_pairs<<<grid, BLOCK, 0, stream>>>(
            positions, embeddings, block_table, pb, out, n);
    } else {
        int nthreads = (n + NPT - 1) / NPT;
        int grid = (nthreads + BLOCK - 1) / BLOCK;
        neural_poisson_interp<<<grid, BLOCK, 0, stream>>>(
            positions, embeddings, block_table, out, n);
    }
}